// Round 13
// baseline (287.547 us; speedup 1.0000x reference)
//
#include <hip/hip_runtime.h>
#include <hip/hip_bf16.h>

#define Bq   32
#define Cq   64
#define NPq  192
#define NOq  72
#define PTS  (NPq * NOq)   // 13824
#define REGD 76
#define OUTD 79

typedef __attribute__((ext_vector_type(8))) short short8;
typedef __attribute__((ext_vector_type(4))) float float4v;

__device__ inline unsigned short f2bf(float x) {
    __hip_bfloat16 h = __float2bfloat16(x);
    return *reinterpret_cast<unsigned short*>(&h);
}
__device__ inline float bf2f(unsigned short u) {
    unsigned int x = ((unsigned int)u) << 16;
    float f;
    __builtin_memcpy(&f, &x, 4);
    return f;
}

// ---------------------------------------------------------------------------
// Phase 0 (once): gated y-blended tables for all 3 stages.
// EXACT R8 structure (grid, LDS layout, scalar ushort stores) -- only change:
// (H,W) are template params so phase-1 index math is magic-mul, not int div.
// ---------------------------------------------------------------------------
template<int H, int W>
__device__ __forceinline__ void build_one(
    const float* __restrict__ feat, unsigned short* __restrict__ tab,
    const float* __restrict__ lw, const int b, const int o,
    float* __restrict__ sRow, const int tid)
{
    constexpr int Wp = W + 1;

    const float ys = 1.0f - (float)o * (1.0f / 71.0f);
    const float iy = ys * (float)(H - 1);
    const float fy = floorf(iy);
    const float wy = iy - fy;
    int iy0 = (int)fy; iy0 = iy0 < 0 ? 0 : (iy0 > H - 1 ? H - 1 : iy0);
    const int iy1 = (iy0 + 1 > H - 1) ? H - 1 : iy0 + 1;
    const float gate = 1.0f / (1.0f + __expf(-lw[o]));

    const float* fb = feat + (size_t)b * 64 * H * W;
    const int iy0W = iy0 * W, iy1W = iy1 * W;

    constexpr int tot = 64 * W;
    for (int idx = tid; idx < tot; idx += 256) {
        const int c = idx / W;               // constexpr W -> magic mul
        const int x = idx - c * W;
        const float* f = fb + c * (H * W);
        sRow[c * Wp + x] = ((1.0f - wy) * f[iy0W + x] + wy * f[iy1W + x]) * gate;
    }
    __syncthreads();

    unsigned short* to = tab + (size_t)(b * NOq + o) * Wp * 64;
    constexpr int tot2 = Wp * 64;
    for (int idx = tid; idx < tot2; idx += 256) {
        const int x = idx >> 6;
        const int c = idx & 63;
        const int xx = (x < W) ? x : (W - 1);
        to[idx] = f2bf(sRow[c * Wp + xx]);
    }
}

__global__ __launch_bounds__(256) void build_tables_kernel(
    const float* __restrict__ f0,   // x2: H=10,W=25
    const float* __restrict__ f1,   // x1: H=20,W=50
    const float* __restrict__ f2,   // x0: H=40,W=100
    const float* __restrict__ lw,
    unsigned short* __restrict__ t0,
    unsigned short* __restrict__ t1,
    unsigned short* __restrict__ t2)
{
    __shared__ float sRow[64 * 101];
    const int tid = threadIdx.x;
    const int o   = blockIdx.x / 96;
    const int sb  = blockIdx.x - o * 96;
    const int s   = sb >> 5;
    const int b   = sb & 31;

    if (s == 0)      build_one<10, 25 >(f0, t0, lw, b, o, sRow, tid);
    else if (s == 1) build_one<20, 50 >(f1, t1, lw, b, o, sRow, tid);
    else             build_one<40, 100>(f2, t2, lw, b, o, sRow, tid);
}

// ---------------------------------------------------------------------------
// Fused pool+head (R11 shape: 256 thr, 768 blocks, 8 head pts/block) with
// latency hiding:  pool = hoisted xp loads + double-buffered tap prefetch;
// head = double-buffered weight LDS with register prefetch (R6 pattern) so
// every 16 KB staging hides behind the previous layer's compute.
// ---------------------------------------------------------------------------
template<int W>
__global__ __launch_bounds__(256) void fused_pool_head_kernel(
    const unsigned short* __restrict__ tab,   // [B][72][W+1][64] bf16
    const float* __restrict__ xsrc, const int xstride,
    const float* __restrict__ lsgi,           // [64][64] this stage
    float* __restrict__ sumFeat,              // [B*NP][64]
    const int stage,
    const float* __restrict__ fc_w,  const float* __restrict__ fc_b,
    const float* __restrict__ cls_w, const float* __restrict__ cls_b,
    const float* __restrict__ cls_ow, const float* __restrict__ cls_ob,
    const float* __restrict__ reg_w, const float* __restrict__ reg_b,
    const float* __restrict__ reg_ow, const float* __restrict__ reg_ob,
    const float* __restrict__ loc_w, const float* __restrict__ loc_b,
    const float* __restrict__ loc_ow, const float* __restrict__ loc_ob,
    float* __restrict__ out, float* __restrict__ xs_next)
{
    constexpr int Wp = W + 1;
    __shared__ __align__(16) float sF [8][68];
    __shared__ __align__(16) float sC [8][68];
    __shared__ __align__(16) float sT1[8][68];
    __shared__ __align__(16) float sT2[8][68];
    __shared__ __align__(16) float sWtA[4864];
    __shared__ __align__(16) float sWtB[4864];

    const int tid  = threadIdx.x;
    const int w    = tid >> 6;
    const int lane = tid & 63;
    const int ng   = blockIdx.x >> 5;         // 0..23
    const int b    = blockIdx.x & 31;
    const int npair = ng * 4 + w;             // 0..95

    // stage fc_w -> sWtA while the pool runs (visibility via head's 1st barrier)
    #pragma unroll
    for (int i = 0; i < 4; ++i)
        *(float4*)&sWtA[(i * 256 + tid) * 4] = *(const float4*)&fc_w[(i * 256 + tid) * 4];

    // ---------------- pool: hoisted addresses + pipelined taps ----------------
    short8 wf[4][2];
    {
        const int kb = ((lane >> 4) & 3) * 8;
        const int dl = lane & 15;
        #pragma unroll
        for (int ks = 0; ks < 2; ++ks)
            #pragma unroll
            for (int dt = 0; dt < 4; ++dt) {
                union { unsigned short u[8]; short8 v; } pk;
                #pragma unroll
                for (int j = 0; j < 8; ++j)
                    pk.u[j] = f2bf(lsgi[(ks * 32 + kb + j) * 64 + dt * 16 + dl]);
                wf[dt][ks] = pk.v;
            }
    }

    const unsigned short* tb = tab + (size_t)b * NOq * Wp * 64;
    const float* xp = xsrc + (size_t)xstride * b;
    const int m  = lane & 15;
    const int kg = lane >> 4;
    const int nt0 = npair * 9;

    // all 9 xp loads + address calc up front (breaks the per-tile 2-level chain)
    float wxa[9];
    const unsigned short* cola[9];
    #pragma unroll
    for (int t = 0; t < 9; ++t) {
        const int pt = (nt0 + t) * 16 + m;
        const int o  = pt % NOq;
        float ixf = xp[pt] * (float)(W - 1);
        ixf = fminf(fmaxf(ixf, 0.0f), (float)(W - 1));
        const float fx = floorf(ixf);
        wxa[t] = ixf - fx;
        cola[t] = tb + ((size_t)o * Wp + (int)fx) * 64 + kg * 8;
    }

    float sums0[4] = {0.f, 0.f, 0.f, 0.f};
    float sums1[4] = {0.f, 0.f, 0.f, 0.f};

    short8 cur0, cur1, cur2, cur3;
    cur0 = *(const short8*)(cola[0]);
    cur1 = *(const short8*)(cola[0] + 64);
    cur2 = *(const short8*)(cola[0] + 32);
    cur3 = *(const short8*)(cola[0] + 96);

    #pragma unroll
    for (int ntl = 0; ntl < 9; ++ntl) {
        short8 nx0, nx1, nx2, nx3;
        if (ntl < 8) {                       // prefetch next tile during MFMA
            nx0 = *(const short8*)(cola[ntl + 1]);
            nx1 = *(const short8*)(cola[ntl + 1] + 64);
            nx2 = *(const short8*)(cola[ntl + 1] + 32);
            nx3 = *(const short8*)(cola[ntl + 1] + 96);
        }

        float wxr[4];
        #pragma unroll
        for (int j = 0; j < 4; ++j) wxr[j] = __shfl(wxa[ntl], kg * 4 + j);

        const bool hi = (ntl * 16 + (kg * 4)) >= NOq;
        #pragma unroll
        for (int dt = 0; dt < 4; ++dt) {
            float4v c0 = {0.f, 0.f, 0.f, 0.f};
            float4v c1 = {0.f, 0.f, 0.f, 0.f};
            c0 = __builtin_amdgcn_mfma_f32_16x16x32_bf16(cur0, wf[dt][0], c0, 0, 0, 0);
            c0 = __builtin_amdgcn_mfma_f32_16x16x32_bf16(cur2, wf[dt][1], c0, 0, 0, 0);
            c1 = __builtin_amdgcn_mfma_f32_16x16x32_bf16(cur1, wf[dt][0], c1, 0, 0, 0);
            c1 = __builtin_amdgcn_mfma_f32_16x16x32_bf16(cur3, wf[dt][1], c1, 0, 0, 0);
            const float v0 = c0[0] + wxr[0] * (c1[0] - c0[0]);
            const float v1 = c0[1] + wxr[1] * (c1[1] - c0[1]);
            const float v2 = c0[2] + wxr[2] * (c1[2] - c0[2]);
            const float v3 = c0[3] + wxr[3] * (c1[3] - c0[3]);
            const float pm0 = fmaxf(fmaxf(v0, v1), 0.f);
            const float pm1 = fmaxf(fmaxf(v2, v3), 0.f);
            const float add = pm0 + pm1;
            if (hi) sums1[dt] += add; else sums0[dt] += add;
        }
        cur0 = nx0; cur1 = nx1; cur2 = nx2; cur3 = nx3;
    }

    #pragma unroll
    for (int dt = 0; dt < 4; ++dt) {
        float v0 = sums0[dt], v1 = sums1[dt];
        v0 += __shfl_xor(v0, 16); v0 += __shfl_xor(v0, 32);
        v1 += __shfl_xor(v1, 16); v1 += __shfl_xor(v1, 32);
        sums0[dt] = v0; sums1[dt] = v1;
    }

    const float invS = 1.0f / (float)(stage + 1);
    if (lane < 16) {
        const size_t row0 = (size_t)(b * NPq + npair * 2) * 64;
        #pragma unroll
        for (int dt = 0; dt < 4; ++dt) {
            const int d = dt * 16 + lane;
            float t0 = sums0[dt] * (1.0f / 36.0f);
            float t1 = sums1[dt] * (1.0f / 36.0f);
            float* p0 = sumFeat + row0 + d;
            float* p1 = sumFeat + row0 + 64 + d;
            if (stage > 0) { t0 += *p0; t1 += *p1; }
            *p0 = t0; *p1 = t1;
            sF[2 * w][d]     = t0 * invS;
            sF[2 * w + 1][d] = t1 * invS;
        }
    }

    // ---------------- head: double-buffered weights, reg prefetch ----------
    const int pt2 = tid >> 5;          // 0..7 local point
    const int dh  = tid & 31;
    const int d0  = dh * 2;
    const int p0g = b * NPq + ng * 8;

    // layer: compute from wbuf; prefetch nextw (nextn floats) into regs during
    // compute; store them into nextbuf after (next layer's entry barrier syncs).
    auto do_gemm = [&](const float (*src)[68], float (*dst)[68],
                       const float* wbuf, const float* __restrict__ gb,
                       const float* __restrict__ nextw, int nextn, float* nextbuf) {
        __syncthreads();                   // wbuf staged + src written
        float4 pf[5];
        const int n4 = nextn >> 2;
        #pragma unroll
        for (int i = 0; i < 5; ++i) {
            const int idx = i * 256 + tid;
            if (idx < n4) pf[i] = *(const float4*)&nextw[idx * 4];
        }
        float a0 = gb[d0], a1 = gb[d0 + 1];
        #pragma unroll 8
        for (int k = 0; k < 64; ++k) {
            const float av = src[pt2][k];
            const float2 w2 = *(const float2*)&wbuf[k * 64 + d0];
            a0 += av * w2.x; a1 += av * w2.y;
        }
        dst[pt2][d0]     = fmaxf(a0, 0.f);
        dst[pt2][d0 + 1] = fmaxf(a1, 0.f);
        #pragma unroll
        for (int i = 0; i < 5; ++i) {
            const int idx = i * 256 + tid;
            if (idx < n4) *(float4*)&nextbuf[idx * 4] = pf[i];
        }
    };

    // fc(A, pf cls1->B) ; cls1(B, pf cls2->A) ; cls2(A, pf reg1->B)
    do_gemm(sF,  sC,  sWtA, fc_b,       cls_w,        4096, sWtB);
    do_gemm(sC,  sT1, sWtB, cls_b,      cls_w + 4096, 4096, sWtA);
    do_gemm(sT1, sT2, sWtA, cls_b + 64, reg_w,        4096, sWtB);
    __syncthreads();
    if (tid < 16) {                        // cls proj (small, straight from L2)
        const int p = tid >> 1, d = tid & 1;
        float z = cls_ob[d];
        #pragma unroll 8
        for (int k = 0; k < 64; ++k) z += sT2[p][k] * cls_ow[k * 2 + d];
        out[(size_t)(p0g + p) * OUTD + d] = z;
    }

    // reg1(B, pf reg2->A) ; reg2(A, pf reg_ow->B)
    do_gemm(sC,  sT1, sWtB, reg_b,      reg_w + 4096, 4096,      sWtA);
    do_gemm(sT1, sT2, sWtA, reg_b + 64, reg_ow,       64 * REGD, sWtB);
    __syncthreads();                       // reg_ow now in B, sT2 ready
    {
        // prefetch loc_w during reg proj
        float4 pf[4];
        #pragma unroll
        for (int i = 0; i < 4; ++i)
            pf[i] = *(const float4*)&loc_w[(i * 256 + tid) * 4];

        float* orow = out + (size_t)(p0g + pt2) * OUTD;
        float* xsp  = xs_next + (size_t)(p0g + pt2) * NOq;
        for (int j = dh; j < REGD; j += 32) {
            float z = reg_ob[j];
            #pragma unroll 8
            for (int k = 0; k < 64; ++k) z += sT2[pt2][k] * sWtB[k * REGD + j];
            orow[2 + j] = z;
            if (j >= 4) xsp[j - 4] = 1.0f / (1.0f + __expf(-z));
        }
        #pragma unroll
        for (int i = 0; i < 4; ++i)
            *(float4*)&sWtA[(i * 256 + tid) * 4] = pf[i];
    }

    // loc1(A, pf loc2->B) ; loc2(B, no prefetch)
    do_gemm(sC,  sT1, sWtA, loc_b,      loc_w + 4096, 4096, sWtB);
    do_gemm(sT1, sT2, sWtB, loc_b + 64, loc_w,        0,    sWtA);
    __syncthreads();
    if (tid < 8) {
        float z = loc_ob[0];
        #pragma unroll 8
        for (int k = 0; k < 64; ++k) z += sT2[tid][k] * loc_ow[k];
        out[(size_t)(p0g + tid) * OUTD + 78] = z;
    }
}

// ---------------------------------------------------------------------------
extern "C" void kernel_launch(void* const* d_in, const int* in_sizes, int n_in,
                              void* d_out, int out_size, void* d_ws, size_t ws_size,
                              hipStream_t stream)
{
    const float* x0        = (const float*)d_in[0];
    const float* x1        = (const float*)d_in[1];
    const float* x2        = (const float*)d_in[2];
    const float* prior_xs0 = (const float*)d_in[3];
    const float* l_weight  = (const float*)d_in[4];
    const float* lsgi_w    = (const float*)d_in[5];
    const float* fc_w      = (const float*)d_in[6];
    const float* fc_b      = (const float*)d_in[7];
    const float* cls_w     = (const float*)d_in[8];
    const float* cls_b     = (const float*)d_in[9];
    const float* cls_ow    = (const float*)d_in[10];
    const float* cls_ob    = (const float*)d_in[11];
    const float* reg_w     = (const float*)d_in[12];
    const float* reg_b     = (const float*)d_in[13];
    const float* reg_ow    = (const float*)d_in[14];
    const float* reg_ob    = (const float*)d_in[15];
    const float* loc_w     = (const float*)d_in[16];
    const float* loc_b     = (const float*)d_in[17];
    const float* loc_ow    = (const float*)d_in[18];
    const float* loc_ob    = (const float*)d_in[19];

    float* out     = (float*)d_out;
    float* sumFeat = (float*)d_ws;                               // [6144][64] f32
    float* xs      = sumFeat + (size_t)Bq * NPq * Cq;            // [6144][72] f32
    unsigned short* tab0 = (unsigned short*)(xs + (size_t)Bq * PTS);
    unsigned short* tab1 = tab0 + (size_t)Bq * NOq * 26  * 64;   // W=25
    unsigned short* tab2 = tab1 + (size_t)Bq * NOq * 51  * 64;   // W=50

    hipLaunchKernelGGL(build_tables_kernel, dim3(3 * Bq * NOq), dim3(256), 0, stream,
                       x2, x1, x0, l_weight, tab0, tab1, tab2);

    for (int s = 0; s < 3; ++s) {
        const float* xsrc = (s == 0) ? prior_xs0 : xs;
        const int xstr    = (s == 0) ? 0 : PTS;
        const unsigned short* tb = (s == 0) ? tab0 : (s == 1) ? tab1 : tab2;
        float* outS = out + (size_t)s * Bq * NPq * OUTD;
        if (s == 0)
            hipLaunchKernelGGL((fused_pool_head_kernel<25>), dim3(Bq * 24), dim3(256), 0, stream,
                               tb, xsrc, xstr, lsgi_w + s * 4096, sumFeat, s,
                               fc_w, fc_b, cls_w, cls_b, cls_ow, cls_ob,
                               reg_w, reg_b, reg_ow, reg_ob,
                               loc_w, loc_b, loc_ow, loc_ob, outS, xs);
        else if (s == 1)
            hipLaunchKernelGGL((fused_pool_head_kernel<50>), dim3(Bq * 24), dim3(256), 0, stream,
                               tb, xsrc, xstr, lsgi_w + s * 4096, sumFeat, s,
                               fc_w, fc_b, cls_w, cls_b, cls_ow, cls_ob,
                               reg_w, reg_b, reg_ow, reg_ob,
                               loc_w, loc_b, loc_ow, loc_ob, outS, xs);
        else
            hipLaunchKernelGGL((fused_pool_head_kernel<100>), dim3(Bq * 24), dim3(256), 0, stream,
                               tb, xsrc, xstr, lsgi_w + s * 4096, sumFeat, s,
                               fc_w, fc_b, cls_w, cls_b, cls_ow, cls_ob,
                               reg_w, reg_b, reg_ow, reg_ob,
                               loc_w, loc_b, loc_ow, loc_ob, outS, xs);
    }
}